// Round 1
// baseline (679.139 us; speedup 1.0000x reference)
//
#include <hip/hip_runtime.h>

#define HW 3136
#define C_ 256
#define T_ 8
#define NPOS 64
#define NBLK_PER_NT 49  // 3136/64
#define YSTRIDE 40      // ushorts per LDS row (32 used + 8 pad) = 80B = 5*16B

typedef __attribute__((ext_vector_type(8))) short bf16x8;
typedef __attribute__((ext_vector_type(4))) float f32x4;
typedef __attribute__((ext_vector_type(4))) unsigned int u32x4;

__device__ __forceinline__ unsigned short f2bf(float f) {
  unsigned int u = __float_as_uint(f);
  u += 0x7FFF + ((u >> 16) & 1);  // round-to-nearest-even
  return (unsigned short)(u >> 16);
}

// ws layout:
// [0,      131072): Wb   bf16 [256][256]  (oc-major, ic contiguous)
// [131072, 132096): ntaps int[256]
// [132096, 140288): dts   int[256*8]
// [140288, 148480): wts   float[256*8]

__global__ void prep_kernel(const float* __restrict__ w1, const float* __restrict__ w3,
                            const float* __restrict__ w5, const float* __restrict__ w7,
                            const float* __restrict__ net_w,
                            unsigned short* __restrict__ Wb, int* __restrict__ ntaps,
                            int* __restrict__ dts, float* __restrict__ wts) {
  int tid = blockIdx.x * blockDim.x + threadIdx.x;
  for (int i = tid; i < C_ * C_; i += gridDim.x * blockDim.x)
    Wb[i] = f2bf(net_w[i]);
  if (tid < C_) {
    int c = tid, g = c >> 6, lc = c & 63, K = 2 * g + 1;
    const float* wsrc = (g == 0) ? w1 : (g == 1) ? w3 : (g == 2) ? w5 : w7;
    int cnt = 0;
    for (int k = 0; k < K; ++k) {
      float v = wsrc[lc * K + k];
      if (v != 0.0f) { dts[c * 8 + cnt] = k - g; wts[c * 8 + cnt] = v; cnt++; }
    }
    ntaps[c] = cnt;
  }
}

// Block: one (n,t) pair x 64 contiguous spatial positions, all 256 output chans.
// 4 waves; wave w computes oc [w*64, w*64+64) via 4x4 grid of 16x16x32 MFMAs.
__global__ __launch_bounds__(256, 2) void fused_kernel(
    const float* __restrict__ x, const unsigned short* __restrict__ Wb,
    const int* __restrict__ ntaps, const int* __restrict__ dts,
    const float* __restrict__ wts, float* __restrict__ out) {
  const int blk = blockIdx.x;
  const int nt = blk / NBLK_PER_NT;
  const int p0 = (blk % NBLK_PER_NT) * NPOS;
  const int n = nt >> 3, t = nt & 7;
  const int tid = threadIdx.x;
  const int lane = tid & 63;
  const int wv = tid >> 6;
  const int m16 = lane & 15;   // MFMA n-index (position) / m-index (oc) per operand
  const int quad = lane >> 4;  // 0..3

  // double-buffered y tile: [64 pos][row stride 40 ushorts = 80B]
  __shared__ __align__(16) unsigned short ylds[2][NPOS * YSTRIDE];

  f32x4 acc[4][4];
#pragma unroll
  for (int i = 0; i < 4; ++i)
#pragma unroll
    for (int j = 0; j < 4; ++j) acc[i][j] = (f32x4){0.f, 0.f, 0.f, 0.f};

  const int pp = tid & 63;     // producer: position within tile (coalesced x loads)
  const int chunk = tid >> 6;  // producer: 8-channel chunk (wave-uniform)

  const size_t xnt_base = (size_t)(n * 8) * C_ * HW + (size_t)(p0 + pp);

  for (int ks = 0; ks < 8; ++ks) {
    const int k0 = ks * 32;
    // ---- producer: y for 8 consecutive channels at position pp ----
    unsigned short pk[8];
#pragma unroll
    for (int j = 0; j < 8; ++j) {
      const int c = k0 + chunk * 8 + j;
      const int ntap = ntaps[c];  // wave-uniform
      float a = 0.f;
      for (int k = 0; k < ntap; ++k) {
        const int tq = t + dts[c * 8 + k];
        if (tq >= 0 && tq < T_) {
          a += wts[c * 8 + k] * x[xnt_base + (size_t)(tq * C_ + c) * HW];
        }
      }
      pk[j] = f2bf(a);
    }
    const int buf = ks & 1;
    *(u32x4*)&ylds[buf][pp * YSTRIDE + chunk * 8] = *(const u32x4*)pk;
    __syncthreads();
    // ---- MFMA phase ----
#pragma unroll
    for (int ni = 0; ni < 4; ++ni) {
      // B[k][n_pos]: n = m16, k = quad*8 + j  (8 consecutive channels, 16B)
      const bf16x8 bfrag = *(const bf16x8*)&ylds[buf][(ni * 16 + m16) * YSTRIDE + quad * 8];
#pragma unroll
      for (int mi = 0; mi < 4; ++mi) {
        // A[m_oc][k]: m = m16, k = quad*8 + j (8 consecutive ic, 16B, L2-resident)
        const int oc = wv * 64 + mi * 16 + m16;
        const bf16x8 afrag = *(const bf16x8*)&Wb[oc * C_ + k0 + quad * 8];
        acc[mi][ni] =
            __builtin_amdgcn_mfma_f32_16x16x32_bf16(afrag, bfrag, acc[mi][ni], 0, 0, 0);
      }
    }
    __syncthreads();  // protects buf reuse 2 steps later + next-step write of buf^1
  }

  // ---- epilogue: D[m][n]: row(oc) = quad*4 + reg, col(pos) = m16 ----
  const size_t obase = (size_t)nt * C_ * HW + p0 + m16;
#pragma unroll
  for (int mi = 0; mi < 4; ++mi) {
#pragma unroll
    for (int r = 0; r < 4; ++r) {
      const int oc = wv * 64 + mi * 16 + quad * 4 + r;
      float* orow = out + obase + (size_t)oc * HW;
#pragma unroll
      for (int ni = 0; ni < 4; ++ni) orow[ni * 16] = acc[mi][ni][r];
    }
  }
}

extern "C" void kernel_launch(void* const* d_in, const int* in_sizes, int n_in,
                              void* d_out, int out_size, void* d_ws, size_t ws_size,
                              hipStream_t stream) {
  const float* x = (const float*)d_in[0];
  const float* w1 = (const float*)d_in[1];
  const float* w3 = (const float*)d_in[2];
  const float* w5 = (const float*)d_in[3];
  const float* w7 = (const float*)d_in[4];
  const float* net_w = (const float*)d_in[5];
  float* out = (float*)d_out;

  char* ws = (char*)d_ws;
  unsigned short* Wb = (unsigned short*)ws;
  int* ntaps = (int*)(ws + 131072);
  int* dts = (int*)(ws + 132096);
  float* wts = (float*)(ws + 140288);

  hipLaunchKernelGGL(prep_kernel, dim3(64), dim3(256), 0, stream,
                     w1, w3, w5, w7, net_w, Wb, ntaps, dts, wts);
  hipLaunchKernelGGL(fused_kernel, dim3(64 * NBLK_PER_NT), dim3(256), 0, stream,
                     x, Wb, ntaps, dts, wts, out);
}

// Round 2
// 435.836 us; speedup vs baseline: 1.5582x; 1.5582x over previous
//
#include <hip/hip_runtime.h>

#define HW 3136
#define C_ 256
#define T_ 8
#define NPOS 64
#define NBLK_PER_NT 49  // 3136/64
#define YSTRIDE 40      // ushorts per LDS row (32 used + 8 pad) = 80B = 5*16B

typedef __attribute__((ext_vector_type(8))) short bf16x8;
typedef __attribute__((ext_vector_type(4))) float f32x4;
typedef __attribute__((ext_vector_type(4))) unsigned int u32x4;
typedef __attribute__((ext_vector_type(4))) int i32x4;

__device__ __forceinline__ unsigned short f2bf(float f) {
  unsigned int u = __float_as_uint(f);
  u += 0x7FFF + ((u >> 16) & 1);  // round-to-nearest-even
  return (unsigned short)(u >> 16);
}

// Per-channel temporal-conv taps, packed to one 16B LDS-friendly struct.
// dts packed as 3 x 8-bit (dt+4); unused slots have w=0, dt=0.
struct TapC { float w0, w1, w2; int dts; };

// ws layout:
// [0,      131072): Wb  bf16 [256][256] (oc-major, ic contiguous)
// [131072, 135168): TapC tab[256]

__global__ void prep_kernel(const float* __restrict__ w1, const float* __restrict__ w3,
                            const float* __restrict__ w5, const float* __restrict__ w7,
                            const float* __restrict__ net_w,
                            unsigned short* __restrict__ Wb, TapC* __restrict__ tab) {
  int tid = blockIdx.x * blockDim.x + threadIdx.x;
  for (int i = tid; i < C_ * C_; i += gridDim.x * blockDim.x)
    Wb[i] = f2bf(net_w[i]);
  if (tid < C_) {
    int c = tid, g = c >> 6, lc = c & 63, K = 2 * g + 1;
    const float* wsrc = (g == 0) ? w1 : (g == 1) ? w3 : (g == 2) ? w5 : w7;
    float w[3] = {0.f, 0.f, 0.f};
    int d[3] = {0, 0, 0};
    int cnt = 0;
    for (int k = 0; k < K && cnt < 3; ++k) {
      float v = wsrc[lc * K + k];
      if (v != 0.0f) { d[cnt] = k - g; w[cnt] = v; cnt++; }
    }
    TapC tc;
    tc.w0 = w[0]; tc.w1 = w[1]; tc.w2 = w[2];
    tc.dts = (d[0] + 4) | ((d[1] + 4) << 8) | ((d[2] + 4) << 16);
    tab[c] = tc;
  }
}

// Block: one (n,t) pair x 64 contiguous spatial positions, all 256 output chans.
// 4 waves; wave w computes oc [w*64, w*64+64) via 4x4 grid of 16x16x32 MFMAs.
__global__ __launch_bounds__(256, 4) void fused_kernel(
    const float* __restrict__ x, const unsigned short* __restrict__ Wb,
    const TapC* __restrict__ tab, float* __restrict__ out) {
  const int blk = blockIdx.x;
  const int nt = blk / NBLK_PER_NT;
  const int p0 = (blk % NBLK_PER_NT) * NPOS;
  const int n = nt >> 3, t = nt & 7;
  const int tid = threadIdx.x;
  const int lane = tid & 63;
  const int wv = tid >> 6;
  const int m16 = lane & 15;
  const int quad = lane >> 4;

  __shared__ __align__(16) unsigned short ylds[2][NPOS * YSTRIDE];  // 10 KiB
  __shared__ __align__(16) TapC ltab[C_];                           // 4 KiB

  // stage tap table to LDS once
  ltab[tid & (C_ - 1)] = tab[tid & (C_ - 1)];

  f32x4 acc[4][4];
#pragma unroll
  for (int i = 0; i < 4; ++i)
#pragma unroll
    for (int j = 0; j < 4; ++j) acc[i][j] = (f32x4){0.f, 0.f, 0.f, 0.f};

  const int pp = tid & 63;     // producer: position within tile (coalesced x loads)
  const int chunk = tid >> 6;  // producer: 8-channel chunk (wave-uniform)

  const float* xbase = x + (size_t)(n * 8) * C_ * HW + (size_t)(p0 + pp);

  __syncthreads();  // ltab ready

  for (int ks = 0; ks < 8; ++ks) {
    const int cbase = ks * 32 + chunk * 8;
    // ---- producer: gather taps (LDS broadcast) + 24 independent x loads ----
    float xv[8][3];
    float wk[8][3];
#pragma unroll
    for (int j = 0; j < 8; ++j) {
      const int c = cbase + j;
      const TapC tc = ltab[c];
      const float tw[3] = {tc.w0, tc.w1, tc.w2};
#pragma unroll
      for (int s = 0; s < 3; ++s) {
        const int dt = ((tc.dts >> (8 * s)) & 0xFF) - 4;
        const int tq = t + dt;
        const bool ok = (unsigned)tq < (unsigned)T_;
        const int tqc = ok ? tq : t;
        wk[j][s] = ok ? tw[s] : 0.f;
        xv[j][s] = xbase[(size_t)((tqc * C_ + c) * HW)];
      }
    }
    unsigned short pk[8];
#pragma unroll
    for (int j = 0; j < 8; ++j) {
      float a = wk[j][0] * xv[j][0] + wk[j][1] * xv[j][1] + wk[j][2] * xv[j][2];
      pk[j] = f2bf(a);
    }
    const int buf = ks & 1;
    *(u32x4*)&ylds[buf][pp * YSTRIDE + chunk * 8] = *(const u32x4*)pk;
    __syncthreads();
    // ---- MFMA phase (double buffer ⇒ single barrier per step is safe:
    //      next write of this buf happens only after the NEXT barrier) ----
    const int k0 = ks * 32;
#pragma unroll
    for (int ni = 0; ni < 4; ++ni) {
      const bf16x8 bfrag = *(const bf16x8*)&ylds[buf][(ni * 16 + m16) * YSTRIDE + quad * 8];
#pragma unroll
      for (int mi = 0; mi < 4; ++mi) {
        const int oc = wv * 64 + mi * 16 + m16;
        const bf16x8 afrag = *(const bf16x8*)&Wb[oc * C_ + k0 + quad * 8];
        acc[mi][ni] =
            __builtin_amdgcn_mfma_f32_16x16x32_bf16(afrag, bfrag, acc[mi][ni], 0, 0, 0);
      }
    }
  }

  // ---- epilogue: D row(oc) = quad*4 + reg, col(pos) = m16 ----
  const size_t obase = (size_t)nt * C_ * HW + p0 + m16;
#pragma unroll
  for (int mi = 0; mi < 4; ++mi) {
#pragma unroll
    for (int r = 0; r < 4; ++r) {
      const int oc = wv * 64 + mi * 16 + quad * 4 + r;
      float* orow = out + obase + (size_t)oc * HW;
#pragma unroll
      for (int ni = 0; ni < 4; ++ni) orow[ni * 16] = acc[mi][ni][r];
    }
  }
}

extern "C" void kernel_launch(void* const* d_in, const int* in_sizes, int n_in,
                              void* d_out, int out_size, void* d_ws, size_t ws_size,
                              hipStream_t stream) {
  const float* x = (const float*)d_in[0];
  const float* w1 = (const float*)d_in[1];
  const float* w3 = (const float*)d_in[2];
  const float* w5 = (const float*)d_in[3];
  const float* w7 = (const float*)d_in[4];
  const float* net_w = (const float*)d_in[5];
  float* out = (float*)d_out;

  char* ws = (char*)d_ws;
  unsigned short* Wb = (unsigned short*)ws;
  TapC* tab = (TapC*)(ws + 131072);

  hipLaunchKernelGGL(prep_kernel, dim3(64), dim3(256), 0, stream,
                     w1, w3, w5, w7, net_w, Wb, tab);
  hipLaunchKernelGGL(fused_kernel, dim3(64 * NBLK_PER_NT), dim3(256), 0, stream,
                     x, Wb, tab, out);
}